// Round 7
// baseline (465.409 us; speedup 1.0000x reference)
//
#include <hip/hip_runtime.h>
#include <cstdint>
#include <cstddef>

// Problem constants
#define B_ 4
#define S_ 2048
#define E_ 1024
#define H_ 16
#define D_ 64
#define M_ (B_*S_)                        // 8192 tokens
#define NE_ ((size_t)B_*H_*S_*D_)         // 8388608 elements per q/k/v buffer

// q pre-scale: 0.125 * log2(e)  (softmax computed with exp2)
#define QSCALE 0.18033688011112042f
// score accumulator init: -16 * log2(e)
#define SINIT  -23.083120654223414f

typedef unsigned int  u32;
typedef unsigned short u16;
typedef __attribute__((ext_vector_type(8))) short bf16x8;
typedef __attribute__((ext_vector_type(4))) float f32x4;

// fp32 -> bf16 (round-to-nearest-even), finite inputs
__device__ __forceinline__ u16 f2bf(float x) {
    u32 u = __float_as_uint(x);
    u32 r = (u + 0x7FFFu + ((u >> 16) & 1u)) >> 16;
    return (u16)r;
}
__device__ __forceinline__ float bf2f(u16 h) { return __uint_as_float((u32)h << 16); }

// async global->LDS 16B DMA: per-lane global addr, wave-uniform LDS base;
// HW writes lane i at ldsbase + i*16 (linear).
__device__ __forceinline__ void gload_lds16(const void* gsrc, void* lds) {
    __builtin_amdgcn_global_load_lds(
        (const __attribute__((address_space(1))) u32*)gsrc,
        (__attribute__((address_space(3))) u32*)lds, 16, 0, 0);
}

// Swizzled 64x64 bf16 tile image layout (8 KB per tile):
//   element offset = r*64 + ((c ^ (r&7))<<3) + (k&7),  r = row 0..63, c = (k>>3)
// Fragment read (16x16x32 MFMA): row r, chunk c_log = kk*4+quad, c_phys = c_log ^ (r&7).

// ---------------------------------------------------------------------------
// convert fp32 matrix (rows x 1024, row-major) -> hi/lo swizzled tile images
// ---------------------------------------------------------------------------
__global__ __launch_bounds__(256)
void convert_img(const float* __restrict__ src, u16* __restrict__ dh, u16* __restrict__ dl)
{
    const int tile = blockIdx.x;
    const int nt = tile >> 4, kt = tile & 15;
    const size_t tb = (size_t)tile << 12;          // u16 elements
    #pragma unroll
    for (int u = 0; u < 2; ++u) {
        const int ci = threadIdx.x + u * 256;      // 0..511
        const int r  = ci >> 3;                    // 0..63
        const int c  = ci & 7;
        const float* s = src + ((size_t)(nt * 64 + r)) * 1024 + kt * 64 + c * 8;
        const float4 f0 = *(const float4*)s;
        const float4 f1 = *(const float4*)(s + 4);
        const float vals[8] = {f0.x, f0.y, f0.z, f0.w, f1.x, f1.y, f1.z, f1.w};
        __align__(16) short hs[8];
        __align__(16) short ls[8];
        #pragma unroll
        for (int j = 0; j < 8; ++j) {
            const u16 h = f2bf(vals[j]);
            hs[j] = (short)h;
            ls[j] = (short)f2bf(vals[j] - bf2f(h));
        }
        const size_t eoff = tb + r * 64 + ((size_t)(c ^ (r & 7)) << 3);
        *(bf16x8*)(dh + eoff) = *(const bf16x8*)hs;
        *(bf16x8*)(dl + eoff) = *(const bf16x8*)ls;
    }
}

// ---------------------------------------------------------------------------
// MFMA GEMM, hi/lo 3-product bf16, PURE-DMA both operands (verified round 5).
// BM=128, BN=128, BK=64, 4 waves in 2x2 (each wave: 64x64 out, 4x4 16-tiles).
// MODE 0 (QKV): epilogue scatters q (natural, scaled by QSCALE) / kh, vh+vl.
// MODE 1 (proj): epilogue plain fp32 + bias.
// ---------------------------------------------------------------------------
template<int MODE>
__global__ __launch_bounds__(256)
void gemm_mfma(const u16* __restrict__ AIh, const u16* __restrict__ AIl,
               const u16* __restrict__ BIh, const u16* __restrict__ BIl,
               const float* __restrict__ bias, float* __restrict__ Cout,
               u16* __restrict__ qh, u16* __restrict__ ql,
               u16* __restrict__ kh,
               u16* __restrict__ vh, u16* __restrict__ vl)
{
    __shared__ __align__(16) u16 sA[2][2][4096];   // [row-sub][hi/lo] 32 KB
    __shared__ __align__(16) u16 sB[2][2][4096];   // [col-sub][hi/lo] 32 KB

    const int tid = threadIdx.x, lane = tid & 63, w = tid >> 6;
    const int quad = lane >> 4, l15 = lane & 15;
    const int m0  = blockIdx.x * 128;
    const int n0  = blockIdx.y * 128;
    const int mt0 = blockIdx.x * 2;
    const int nt0 = blockIdx.y * 2;
    const int rw  = w >> 1;
    const int cw  = w & 1;
    const int isB = w >> 1;
    const int sbw = w & 1;

    f32x4 acc[4][4];
    #pragma unroll
    for (int i = 0; i < 4; ++i)
        #pragma unroll
        for (int j = 0; j < 4; ++j)
            acc[i][j] = (f32x4){0.f, 0.f, 0.f, 0.f};

    for (int kt = 0; kt < 16; ++kt) {
        __syncthreads();
        {
            const size_t atile = ((size_t)((mt0 + sbw) * 16 + kt)) << 12;  // u16
            const size_t btile = ((size_t)((nt0 + sbw) * 16 + kt)) << 12;
            const u16* srcH = isB ? (BIh + btile) : (AIh + atile);
            const u16* srcL = isB ? (BIl + btile) : (AIl + atile);
            u16* dstH = isB ? &sB[sbw][0][0] : &sA[sbw][0][0];
            u16* dstL = isB ? &sB[sbw][1][0] : &sA[sbw][1][0];
            #pragma unroll
            for (int it = 0; it < 8; ++it)
                gload_lds16(srcH + it * 512 + lane * 8, dstH + it * 512);
            #pragma unroll
            for (int it = 0; it < 8; ++it)
                gload_lds16(srcL + it * 512 + lane * 8, dstL + it * 512);
        }
        __syncthreads();

        #pragma unroll
        for (int kk = 0; kk < 2; ++kk) {
            bf16x8 aH[4], aL[4], bH[4], bL[4];
            #pragma unroll
            for (int i = 0; i < 4; ++i) {
                const int r = i * 16 + l15;
                const int off = r * 64 + (((kk * 4 + quad) ^ (r & 7)) << 3);
                aH[i] = *(const bf16x8*)&sA[rw][0][off];
                aL[i] = *(const bf16x8*)&sA[rw][1][off];
            }
            #pragma unroll
            for (int j = 0; j < 4; ++j) {
                const int r = j * 16 + l15;
                const int off = r * 64 + (((kk * 4 + quad) ^ (r & 7)) << 3);
                bH[j] = *(const bf16x8*)&sB[cw][0][off];
                bL[j] = *(const bf16x8*)&sB[cw][1][off];
            }
            #pragma unroll
            for (int i = 0; i < 4; ++i)
                #pragma unroll
                for (int j = 0; j < 4; ++j) {
                    acc[i][j] = __builtin_amdgcn_mfma_f32_16x16x32_bf16(aL[i], bH[j], acc[i][j], 0, 0, 0);
                    acc[i][j] = __builtin_amdgcn_mfma_f32_16x16x32_bf16(aH[i], bL[j], acc[i][j], 0, 0, 0);
                    acc[i][j] = __builtin_amdgcn_mfma_f32_16x16x32_bf16(aH[i], bH[j], acc[i][j], 0, 0, 0);
                }
        }
    }

    const int fbase = n0 + cw * 64;
    float bj[4];
    #pragma unroll
    for (int j = 0; j < 4; ++j) bj[j] = bias[fbase + j * 16 + l15];

    if (MODE == 0) {
        const int cR = fbase >> 10;
        const int hh = (fbase >> 6) & 15;
        #pragma unroll
        for (int i = 0; i < 4; ++i)
            #pragma unroll
            for (int j = 0; j < 4; ++j)
                #pragma unroll
                for (int reg = 0; reg < 4; ++reg) {
                    float val = acc[i][j][reg] + bj[j];
                    const int m = m0 + rw * 64 + i * 16 + quad * 4 + reg;
                    const int d = j * 16 + l15;
                    const int bb = m >> 11, s = m & 2047;
                    const int bh = bb * 16 + hh;
                    if (cR == 0) val *= QSCALE;    // fold 1/8 and log2(e)
                    const u16 h = f2bf(val);
                    if (cR == 0) {
                        const u16 lo = f2bf(val - bf2f(h));
                        const size_t idx = ((size_t)bh * 2048 + s) * 64 + d;
                        qh[idx] = h; ql[idx] = lo;
                    } else if (cR == 1) {
                        const size_t tile = (size_t)bh * 32 + (s >> 6);
                        const int r = s & 63;
                        const size_t off = (tile << 12) + r * 64 + (((d >> 3) ^ (r & 7)) << 3) + (d & 7);
                        kh[off] = h;
                    } else {
                        const u16 lo = f2bf(val - bf2f(h));
                        const size_t tile = (size_t)bh * 32 + (s >> 6);
                        const size_t off = (tile << 12) + d * 64 + ((((s & 63) >> 3) ^ (d & 7)) << 3) + (s & 7);
                        vh[off] = h; vl[off] = lo;
                    }
                }
    } else {
        #pragma unroll
        for (int i = 0; i < 4; ++i)
            #pragma unroll
            for (int j = 0; j < 4; ++j)
                #pragma unroll
                for (int reg = 0; reg < 4; ++reg) {
                    const int m = m0 + rw * 64 + i * 16 + quad * 4 + reg;
                    const int f = fbase + j * 16 + l15;
                    Cout[(size_t)m * 1024 + f] = acc[i][j][reg] + bj[j];
                }
    }
}

// ---------------------------------------------------------------------------
// MFMA flash attention v3: 256-q blocks (8 waves), fixed-max exp2 softmax,
// S^T score layout (K as A-operand) so each lane holds 4 contiguous k's ->
// P stores are 8 ds_write_b64 per wave-kt instead of 32 ds_write_b16.
// QK^T = Kh x (Qh+Ql); PV = Ph x (Vh+Vl); l from exact fp32 p.
// Grid 8 x 64 = 512 blocks = exactly 2 blocks/CU (no tail).
// ---------------------------------------------------------------------------
__global__ __launch_bounds__(512, 4)
void attn_mfma(const u16* __restrict__ qh, const u16* __restrict__ ql,
               const u16* __restrict__ kh,
               const u16* __restrict__ vh, const u16* __restrict__ vl,
               u16* __restrict__ oh, u16* __restrict__ ol)
{
    __shared__ __align__(16) u16 KV[3][4096];     // Khi Vthi Vtlo (24 KB)
    __shared__ __align__(16) u16 Psh[8][2304];    // per-wave P [32 q][stride 72] (36 KB)

    const int tid  = threadIdx.x;
    const int lane = tid & 63, w = tid >> 6;      // w = 0..7
    const int quad = lane >> 4, l15 = lane & 15;
    const int bh = blockIdx.y;
    const int q0 = blockIdx.x * 256 + w * 32;

    // Q A-frags in registers: lane holds Q[q=l15][k=kk*32+quad*8+j]
    bf16x8 Qf[2][2][2];
    #pragma unroll
    for (int qs = 0; qs < 2; ++qs)
        #pragma unroll
        for (int kk = 0; kk < 2; ++kk) {
            const size_t idx = ((size_t)bh * S_ + q0 + qs * 16 + l15) * 64 + kk * 32 + quad * 8;
            Qf[qs][kk][0] = *(const bf16x8*)(qh + idx);
            Qf[qs][kk][1] = *(const bf16x8*)(ql + idx);
        }

    f32x4 O[2][4];
    float l_lane[2] = {0.f, 0.f};                 // per-lane partial of l[q=l15]
    #pragma unroll
    for (int qs = 0; qs < 2; ++qs)
        #pragma unroll
        for (int ds = 0; ds < 4; ++ds)
            O[qs][ds] = (f32x4){0.f, 0.f, 0.f, 0.f};

    const char* gk[3] = {(const char*)kh, (const char*)vh, (const char*)vl};

    for (int kt = 0; kt < S_ / 64; ++kt) {
        __syncthreads();
        const size_t tb = (((size_t)bh * 32 + kt) << 13);
        #pragma unroll
        for (int a = 0; a < 3; ++a)
            gload_lds16(gk[a] + tb + w * 1024 + lane * 16, (char*)&KV[a][0] + w * 1024);
        __syncthreads();   // DMA drained (vmcnt at barrier)

        // ---- S^T[key][q]: mfma(Kh, Q{lo,hi}); acc init = -16*log2e ----
        f32x4 ST[4][2];
        #pragma unroll
        for (int kst = 0; kst < 4; ++kst)
            #pragma unroll
            for (int qs = 0; qs < 2; ++qs)
                ST[kst][qs] = (f32x4){SINIT, SINIT, SINIT, SINIT};

        #pragma unroll
        for (int kst = 0; kst < 4; ++kst) {
            const int r = kst * 16 + l15;
            #pragma unroll
            for (int kk = 0; kk < 2; ++kk) {
                const int c = (kk * 4 + quad) ^ (r & 7);
                const bf16x8 Kh = *(const bf16x8*)&KV[0][r * 64 + c * 8];
                #pragma unroll
                for (int qs = 0; qs < 2; ++qs) {
                    ST[kst][qs] = __builtin_amdgcn_mfma_f32_16x16x32_bf16(Kh, Qf[qs][kk][1], ST[kst][qs], 0, 0, 0);
                    ST[kst][qs] = __builtin_amdgcn_mfma_f32_16x16x32_bf16(Kh, Qf[qs][kk][0], ST[kst][qs], 0, 0, 0);
                }
            }
        }

        // ---- p = exp2(S^T); lane's 4 regs are contiguous k's at q=l15 ----
        #pragma unroll
        for (int kst = 0; kst < 4; ++kst)
            #pragma unroll
            for (int qs = 0; qs < 2; ++qs) {
                float p[4];
                #pragma unroll
                for (int reg = 0; reg < 4; ++reg)
                    p[reg] = exp2f(ST[kst][qs][reg]);
                l_lane[qs] += (p[0] + p[1]) + (p[2] + p[3]);
                uint2 pk;
                pk.x = (u32)f2bf(p[0]) | ((u32)f2bf(p[1]) << 16);
                pk.y = (u32)f2bf(p[2]) | ((u32)f2bf(p[3]) << 16);
                *(uint2*)&Psh[w][(qs * 16 + l15) * 72 + kst * 16 + quad * 4] = pk;
            }

        // ---- PV: O += P @ (Vh+Vl); same-wave LDS dependence, no barrier ----
        #pragma unroll
        for (int kk = 0; kk < 2; ++kk) {
            bf16x8 PhF[2];
            #pragma unroll
            for (int qs = 0; qs < 2; ++qs) {
                const int pidx = (qs * 16 + l15) * 72 + kk * 32 + quad * 8;
                PhF[qs] = *(const bf16x8*)&Psh[w][pidx];
            }
            #pragma unroll
            for (int ds = 0; ds < 4; ++ds) {
                const int r = ds * 16 + l15;
                const int c = (kk * 4 + quad) ^ (r & 7);
                const bf16x8 Vh = *(const bf16x8*)&KV[1][r * 64 + c * 8];
                const bf16x8 Vl = *(const bf16x8*)&KV[2][r * 64 + c * 8];
                #pragma unroll
                for (int qs = 0; qs < 2; ++qs) {
                    O[qs][ds] = __builtin_amdgcn_mfma_f32_16x16x32_bf16(PhF[qs], Vl, O[qs][ds], 0, 0, 0);
                    O[qs][ds] = __builtin_amdgcn_mfma_f32_16x16x32_bf16(PhF[qs], Vh, O[qs][ds], 0, 0, 0);
                }
            }
        }
    }

    // ---- l reduction across quads (lanes xor 16, 32); then broadcast ----
    float linv[2];
    #pragma unroll
    for (int qs = 0; qs < 2; ++qs) {
        float rs = l_lane[qs];
        rs += __shfl_xor(rs, 16);
        rs += __shfl_xor(rs, 32);
        linv[qs] = 1.f / rs;                      // valid for q = l15 (all quads)
    }

    // ---- epilogue: normalize, hi/lo split, write swizzled o-image tiles ----
    const int bb = bh >> 4, hh = bh & 15;
    #pragma unroll
    for (int qs = 0; qs < 2; ++qs)
        #pragma unroll
        for (int reg = 0; reg < 4; ++reg) {
            const float inv = __shfl(linv[qs], quad * 4 + reg, 16);
            const int s = q0 + qs * 16 + quad * 4 + reg;
            const int m = bb * 2048 + s;
            const int mt = m >> 6, r = m & 63;
            const size_t tbase = ((size_t)(mt * 16 + hh)) << 12;
            #pragma unroll
            for (int ds = 0; ds < 4; ++ds) {
                const int d = ds * 16 + l15;
                const float val = O[qs][ds][reg] * inv;
                const u16 h  = f2bf(val);
                const u16 lo = f2bf(val - bf2f(h));
                const size_t off = tbase + r * 64 + (((d >> 3) ^ (r & 7)) << 3) + (d & 7);
                oh[off] = h; ol[off] = lo;
            }
        }
}

// ---------------------------------------------------------------------------
extern "C" void kernel_launch(void* const* d_in, const int* in_sizes, int n_in,
                              void* d_out, int out_size, void* d_ws, size_t ws_size,
                              hipStream_t stream) {
    const float* x      = (const float*)d_in[0];
    const float* w_qkv  = (const float*)d_in[1];
    const float* b_qkv  = (const float*)d_in[2];
    const float* w_proj = (const float*)d_in[3];
    const float* b_proj = (const float*)d_in[4];
    float* out = (float*)d_out;

    // ws (130 MB): qh ql kh vh vl | xh xl (-> oh ol) | wqh wql (-> wph wpl)
    u16* qh  = (u16*)d_ws;
    u16* ql  = qh + NE_;
    u16* kh  = ql + NE_;
    u16* vh  = kh + NE_;
    u16* vl  = vh + NE_;
    u16* xh  = vl + NE_;
    u16* xl  = xh + NE_;
    u16* wqh = xl + NE_;
    u16* wql = wqh + (size_t)3 * 1024 * 1024;
    u16* oh  = xh;                         // alias (x dead after QKV)
    u16* ol  = xl;
    u16* wph = wqh;                        // alias (wq dead after QKV)
    u16* wpl = wph + (size_t)1024 * 1024;

    // Phase 0: one-time conversions to hi/lo swizzled tile images
    convert_img<<<(M_ / 64) * 16, 256, 0, stream>>>(x, xh, xl);
    convert_img<<<48 * 16, 256, 0, stream>>>(w_qkv, wqh, wql);

    {   // Phase 1: QKV GEMM (pure-DMA MFMA)
        dim3 grid(M_ / 128, (3 * E_) / 128);
        gemm_mfma<0><<<grid, 256, 0, stream>>>(xh, xl, wqh, wql,
                                               b_qkv, nullptr, qh, ql, kh, vh, vl);
    }
    {   // Phase 2: MFMA flash attention (8-wave blocks, 2/CU exactly)
        dim3 grid(S_ / 256, B_ * H_);          // 8 x 64
        attn_mfma<<<grid, 512, 0, stream>>>(qh, ql, kh, vh, vl, oh, ol);
    }
    convert_img<<<16 * 16, 256, 0, stream>>>(w_proj, wph, wpl);
    {   // Phase 3: proj GEMM (pure-DMA MFMA)
        dim3 grid(M_ / 128, E_ / 128);
        gemm_mfma<1><<<grid, 256, 0, stream>>>(oh, ol, wph, wpl,
                                               b_proj, out, nullptr, nullptr, nullptr,
                                               nullptr, nullptr);
    }
}